// Round 3
// baseline (727.936 us; speedup 1.0000x reference)
//
#include <hip/hip_runtime.h>
#include <stdint.h>

// Problem constants: B=1, C=32, Z=64, Y=256, X=256
#define ZS 64
#define CS 32
#define YX 65536          // rays
#define RPB 64            // rays per block
#define FAR_DIST 1e10f
#define NLD 65            // padded leading dim for noise tile

// One block = 64 consecutive rays, 256 threads (4 waves).
// Phase 0: stage noise[64 rays][64 z] into LDS via coalesced float4 loads.
// Phase 1: wave 0, one ray/lane: sequential alpha/transmittance chain,
//          weights -> w_lds[z][ray]; acc_map store.
// Phase 2: thread = (ray-quad 0..15, channel-group 0..15); float4 feat loads
//          (global_load_dwordx4, 1 KiB/wave-instr), ds_read_b128 weights.
__global__ __launch_bounds__(256) void rendernet_kernel(
    const float* __restrict__ feat,   // [C,Z,Y,X]
    const float* __restrict__ occ,    // [Z,Y,X]
    const float* __restrict__ zd,     // [Z]
    const float* __restrict__ noise,  // [N,Z]
    float* __restrict__ out)          // loss(1) + rgb(C*YX) + fe(C*YX) + acc(YX)
{
    __shared__ float w_lds[ZS * RPB];            // 16 KiB, [z][ray]
    __shared__ float noise_lds[RPB * NLD];       // 16.6 KiB, [ray][z] pad+1
    __shared__ float dist_s[ZS];

    const int t  = threadIdx.x;
    const int r0 = blockIdx.x * RPB;

    // ---- Phase 0: stage noise (block tile contiguous in global) ----
    const float4* ng = reinterpret_cast<const float4*>(noise + (size_t)r0 * ZS);
    #pragma unroll
    for (int j = 0; j < 4; ++j) {
        int idx = j * 256 + t;            // 0..1023 float4s
        float4 v = ng[idx];
        int ray = idx >> 4;               // 16 float4 = 64 z per ray
        int zb  = (idx & 15) * 4;
        float* p = &noise_lds[ray * NLD + zb];
        p[0] = v.x; p[1] = v.y; p[2] = v.z; p[3] = v.w;
    }
    if (t < ZS) {
        float a = zd[t];
        dist_s[t] = (t < ZS - 1) ? (zd[t + 1] - a) : FAR_DIST;
    }
    __syncthreads();

    // ---- Phase 1: weights (sequential over z), wave 0 only ----
    if (t < RPB) {
        const int n = r0 + t;
        float T = 1.0f, wsum = 0.0f;
        #pragma unroll 8
        for (int z = 0; z < ZS; ++z) {
            float o   = occ[(size_t)z * YX + n];       // coalesced
            float ns  = noise_lds[t * NLD + z];        // 2-way alias: free
            float raw = fmaxf(o + ns * 0.1f, 0.0f);
            float alpha = 1.0f - __expf(-raw * dist_s[z]);
            float w = alpha * T;
            w_lds[z * RPB + t] = w;
            wsum += w;
            T *= (1.0f - alpha + 1e-10f);
        }
        out[(size_t)1 + 2u * (size_t)CS * YX + n] = fminf(fmaxf(wsum, 0.0f), 1.0f);
        if (blockIdx.x == 0 && t == 0) out[0] = 0.0f;  // total_loss
    }
    __syncthreads();

    // ---- Phase 2: float4 feature composite ----
    const int quad = t & 15;             // ray quad: rays r0+quad*4 .. +3
    const int cg   = t >> 4;             // 0..15 -> channels {cg, cg+16}
    const int c0   = cg, c1 = cg + 16;

    const float4* w4 = reinterpret_cast<const float4*>(w_lds);
    const float4* f0 = reinterpret_cast<const float4*>(feat + (size_t)c0 * ZS * YX + r0);
    const float4* f1 = reinterpret_cast<const float4*>(feat + (size_t)c1 * ZS * YX + r0);

    float4 a0 = {0.f, 0.f, 0.f, 0.f};
    float4 a1 = {0.f, 0.f, 0.f, 0.f};

    #pragma unroll 4
    for (int z = 0; z < ZS; ++z) {
        float4 w  = w4[z * (RPB / 4) + quad];              // ds_read_b128
        float4 v0 = f0[(size_t)z * (YX / 4) + quad];       // dwordx4, coalesced
        float4 v1 = f1[(size_t)z * (YX / 4) + quad];
        a0.x += w.x * v0.x; a0.y += w.y * v0.y; a0.z += w.z * v0.z; a0.w += w.w * v0.w;
        a1.x += w.x * v1.x; a1.y += w.y * v1.y; a1.z += w.z * v1.z; a1.w += w.w * v1.w;
    }

    float* rgb = out + 1;
    float* fe  = out + 1 + (size_t)CS * YX;
    const int n = r0 + quad * 4;

    float av0[4] = {a0.x, a0.y, a0.z, a0.w};
    float av1[4] = {a1.x, a1.y, a1.z, a1.w};
    #pragma unroll
    for (int j = 0; j < 4; ++j) {
        size_t o0 = (size_t)c0 * YX + n + j;
        size_t o1 = (size_t)c1 * YX + n + j;
        fe[o0]  = av0[j];
        fe[o1]  = av1[j];
        rgb[o0] = 1.0f / (1.0f + __expf(-av0[j])) - 0.5f;
        rgb[o1] = 1.0f / (1.0f + __expf(-av1[j])) - 0.5f;
    }
}

extern "C" void kernel_launch(void* const* d_in, const int* in_sizes, int n_in,
                              void* d_out, int out_size, void* d_ws, size_t ws_size,
                              hipStream_t stream) {
    const float* feat  = (const float*)d_in[0];
    const float* occ   = (const float*)d_in[1];
    const float* zdist = (const float*)d_in[2];
    const float* noise = (const float*)d_in[3];
    float* out = (float*)d_out;

    rendernet_kernel<<<YX / RPB, 256, 0, stream>>>(feat, occ, zdist, noise, out);
}